// Round 9
// baseline (167.593 us; speedup 1.0000x reference)
//
#include <hip/hip_runtime.h>
#include <stdint.h>

// Problem constants: t_q=64, t_k=128, b=32, n=1024
//   query (64,32,1024) f32 ; keys (128,32,1024) f32 ; Wq,Wk (1024,1024) f32
//   out0 = context (64,32,1024) f32 ; out1 = scores_softmax (64,32,128) f32
//
// Pipeline v10:
//  1) convert: f32->bf16 (q,k,Wq,Wk) + vnorm
//  2) proj_gemm (BK=128, 768 blocks; R4 config — best measured):
//       q-side ej = exp2((q*Wq^T + bias)*C2);
//       k-side ek2 = exp2((k*Wk^T)*C2) stored TRANSPOSED [b][u][k]
//  3) score_all q-split: grid (32 b, 32 qt) = 1024 blocks x 512 thr
//     (4 blk/CU = 32 waves/CU; 8 waves/SIMD covers the inner-loop L2 load
//     latency that capped v3 at 48% VALUBusy). Each block: 2 q-rows, full u,
//     full k; same inner loop + same u-summation order as v3 (bit-identical
//     scores) -> LDS reduce -> softmax (once) -> out_sc -> context GEMV.

typedef __attribute__((ext_vector_type(8))) short bf16x8;
typedef __attribute__((ext_vector_type(4))) float f32x4;

#define C2_SCALE 2.8853900817779268f   // 2*log2(e)

__device__ __forceinline__ unsigned short f2bf(float x) {
    union { float f; uint32_t u; } v; v.f = x;
    uint32_t u = v.u;
    u += 0x7fffu + ((u >> 16) & 1u);   // round-to-nearest-even
    return (unsigned short)(u >> 16);
}

__device__ __forceinline__ float wave_sum(float x) {
#pragma unroll
    for (int off = 32; off; off >>= 1) x += __shfl_xor(x, off);
    return x;
}
__device__ __forceinline__ float wave_max(float x) {
#pragma unroll
    for (int off = 32; off; off >>= 1) x = fmaxf(x, __shfl_xor(x, off));
    return x;
}

// async 16B global -> LDS (wave-uniform base + lane*16 semantics)
__device__ __forceinline__ void gl2lds16(const void* g, void* l) {
    __builtin_amdgcn_global_load_lds(
        (const __attribute__((address_space(1))) void*)g,
        (__attribute__((address_space(3))) void*)l, 16, 0, 0);
}

// ------- f32 -> bf16 conversion of all 4 tensors + fused vnorm (blk 8192) ---
__global__ __launch_bounds__(256) void convert_kernel(
    const float* __restrict__ q, const float* __restrict__ k,
    const float* __restrict__ wq, const float* __restrict__ wk,
    unsigned short* __restrict__ qb, unsigned short* __restrict__ kb,
    unsigned short* __restrict__ wqb, unsigned short* __restrict__ wkb,
    const float* __restrict__ la, const float* __restrict__ ns,
    float* __restrict__ v) {
    __shared__ float red[4], red2[4];
    if (blockIdx.x == 8192) {
        // vnorm: v = la/||la|| * ns; v[1024] = sum(v)
        int tid = threadIdx.x, w = tid >> 6;
        float s = 0.f;
        for (int i = tid; i < 1024; i += 256) { float x = la[i]; s += x * x; }
        s = wave_sum(s);
        if ((tid & 63) == 0) red[w] = s;
        __syncthreads();
        float scale = rsqrtf(red[0] + red[1] + red[2] + red[3]) * ns[0];
        float vp = 0.f;
        for (int i = tid; i < 1024; i += 256) { float vv = la[i] * scale; v[i] = vv; vp += vv; }
        vp = wave_sum(vp);
        if ((tid & 63) == 0) red2[w] = vp;
        __syncthreads();
        if (tid == 0) v[1024] = red2[0] + red2[1] + red2[2] + red2[3];
        return;
    }
    int idx = blockIdx.x * 256 + threadIdx.x;   // float4 index; 2097152 total
    int e = idx * 4;
    const float* src; unsigned short* dst; int off;
    if (e < 2097152)      { src = q;  dst = qb;  off = e; }
    else if (e < 6291456) { src = k;  dst = kb;  off = e - 2097152; }
    else if (e < 7340032) { src = wq; dst = wqb; off = e - 6291456; }
    else                  { src = wk; dst = wkb; off = e - 7340032; }
    float4 xv = *(const float4*)(src + off);
    ushort4 o;
    o.x = f2bf(xv.x); o.y = f2bf(xv.y); o.z = f2bf(xv.z); o.w = f2bf(xv.w);
    *(ushort4*)(dst + off) = o;
}

// ---------------- combined projection GEMM (bf16 -> f32), BK=128 ------------
// Row-group swizzle: XCD = linear_id % 8 = blockIdx.x (since 8 | 8*y).
//   rowt = blockIdx.x * 12 + (blockIdx.y >> 3)   (0..95)
//   col0 = (blockIdx.y & 7) * 128
// rowt 0..31  -> q-part: rows (q*32+b) consecutive, arow = rowt*64
//                epilogue: ej[row][col] = exp2((acc + bias[col])*C2)
// rowt 32..95 -> k-part: t = rowt-32: b0 = t&31, k0 = (t>>5)*64
//                row set = {(k0+s)*32 + b0 : s = 0..63}  (fixed b!)
//                epilogue: LDS transpose -> ek2[(b0*1024+u)*128 + k]
// 64-row x 128-col tile, BK=128: 8 K-iters x (12 gl2lds + 32 MFMA).
// LDS 16+32 KB; epilogue 33 KB aliases. Grid (8, 96) = 768 blocks (3/CU).
// XOR swizzle: LDS[row][c] = global[row][c ^ (row&15)], c = 8-elem chunk 0..15
__global__ __launch_bounds__(256) void proj_gemm(
    const unsigned short* __restrict__ qb, const unsigned short* __restrict__ kb,
    const unsigned short* __restrict__ wqb, const unsigned short* __restrict__ wkb,
    const float* __restrict__ bias,
    float* __restrict__ ej, float* __restrict__ ek2) {
    __shared__ __align__(16) unsigned char smem[49152];
    unsigned short* As = (unsigned short*)smem;             // 16 KB [64][128]
    unsigned short* Bs = (unsigned short*)(smem + 16384);   // 32 KB [128][128]
    float* ep = (float*)smem;                               // 33 KB, k-epilogue only

    int col0 = (blockIdx.y & 7) * 128;
    int rowt = blockIdx.x * 12 + (blockIdx.y >> 3);   // 0..95
    int tid = threadIdx.x;
    int w = tid >> 6, lane = tid & 63;
    int wm = w >> 1, wn = w & 1;          // 2x2 waves
    int ml = lane & 15, quad = lane >> 4;

    bool is_k = rowt >= 32;
    const unsigned short* A; const unsigned short* Bm;
    int base, rstride, arow = 0, b0 = 0, k0g = 0;
    if (!is_k) {
        A = qb; Bm = wqb; arow = rowt * 64;
        base = arow * 1024; rstride = 1024;
    } else {
        int t = rowt - 32;
        b0 = t & 31; k0g = (t >> 5) * 64;
        A = kb; Bm = wkb;
        base = (k0g * 32 + b0) * 1024; rstride = 32 * 1024;
    }

    // staging: 16 lanes/row (256B = BK), 16 rows per gl2lds call
    int srow = tid >> 4;                       // 0..15
    int kxor = (tid & 15) ^ srow;              // row&15 == srow for all calls
    const unsigned short* ga = A + base + srow * rstride + kxor * 8;
    const unsigned short* gb = Bm + (col0 + srow) * 1024 + kxor * 8;
    unsigned short* la = &As[tid * 8];
    unsigned short* lb = &Bs[tid * 8];

    f32x4 acc[2][4];
#pragma unroll
    for (int i = 0; i < 2; i++)
#pragma unroll
        for (int j = 0; j < 4; j++) acc[i][j] = (f32x4)(0.f);

    for (int kk0 = 0; kk0 < 1024; kk0 += 128) {
        __syncthreads();
#pragma unroll
        for (int t = 0; t < 4; t++)
            gl2lds16(ga + t * 16 * rstride + kk0, la + t * 2048);
#pragma unroll
        for (int t = 0; t < 8; t++)
            gl2lds16(gb + t * 16 * 1024 + kk0, lb + t * 2048);
        __syncthreads();
#pragma unroll
        for (int ks = 0; ks < 4; ks++) {
            int kcol = ((ks * 4 + quad) ^ ml) * 8;
            bf16x8 a[2], b[4];
#pragma unroll
            for (int i = 0; i < 2; i++)
                a[i] = *(const bf16x8*)&As[(wm * 32 + i * 16 + ml) * 128 + kcol];
#pragma unroll
            for (int j = 0; j < 4; j++)
                b[j] = *(const bf16x8*)&Bs[(wn * 64 + j * 16 + ml) * 128 + kcol];
#pragma unroll
            for (int i = 0; i < 2; i++)
#pragma unroll
                for (int j = 0; j < 4; j++)
                    acc[i][j] = __builtin_amdgcn_mfma_f32_16x16x32_bf16(a[i], b[j], acc[i][j], 0, 0, 0);
        }
    }

    // C/D layout: col = lane&15, row = quad*4 + reg
    if (!is_k) {
        // q-part: ej = exp2((acc + bias)*C2), straight row-major store
#pragma unroll
        for (int i = 0; i < 2; i++)
#pragma unroll
            for (int j = 0; j < 4; j++) {
                int colg = col0 + wn * 64 + j * 16 + ml;
                float bj = bias[colg];
#pragma unroll
                for (int r = 0; r < 4; r++) {
                    int row = arow + wm * 32 + i * 16 + quad * 4 + r;
                    ej[row * 1024 + colg] =
                        __builtin_amdgcn_exp2f((acc[i][j][r] + bj) * C2_SCALE);
                }
            }
    } else {
        // k-part: exp2, restage through LDS, store transposed (k innermost)
        __syncthreads();   // all waves done reading As/Bs before ep overwrite
#pragma unroll
        for (int i = 0; i < 2; i++)
#pragma unroll
            for (int j = 0; j < 4; j++) {
                int col = wn * 64 + j * 16 + ml;
#pragma unroll
                for (int r = 0; r < 4; r++) {
                    int krel = wm * 32 + i * 16 + quad * 4 + r;
                    ep[krel * 129 + col] =
                        __builtin_amdgcn_exp2f(acc[i][j][r] * C2_SCALE);
                }
            }
        __syncthreads();
        int ur = tid >> 4;            // 0..15
        int kq = (tid & 15) * 4;      // k quad base 0..60
#pragma unroll
        for (int it = 0; it < 8; it++) {
            int u = it * 16 + ur;     // 0..127
            float4 o;
            o.x = ep[(kq + 0) * 129 + u];
            o.y = ep[(kq + 1) * 129 + u];
            o.z = ep[(kq + 2) * 129 + u];
            o.w = ep[(kq + 3) * 129 + u];
            *(float4*)(ek2 + (b0 * 1024 + col0 + u) * 128 + k0g + kq) = o;
        }
    }
}

// ---------------- merged score + softmax + context, q-split -----------------
// Grid (32 b, 32 qt) = 1024 blocks, 512 thr, launch_bounds(512,8) -> <=64
// VGPR, 4 blocks/CU = 32 waves/CU (8 waves/SIMD: inner-loop L2 latency (~200
// cy) covered by ~7 other waves x ~80 cy of compute).
// Block: 2 q-rows (q0 = qt*2), full u (1024), full k (128).
// Phase 1: thread (kp = tid&63 k-pair, uc = tid>>6 128-u chunk). ej[2][1024]
//   + v[1024] broadcast from LDS; ek2 streamed coalesced. Pairing identity
//   over adjacent u: v0/(1+A)+v1/(1+B) = (v0*B1+v1*A1)*rcp(A1*B1). Same u
//   partition + summation order as v3 -> bit-identical scores.
// Phase 2: LDS-combine 8 uc partials -> sc = vsum - 2*s; softmax (once);
//   write out_sc. Phase 3: context GEMV (2 n x 2 q per thread; keys slab
//   L2-resident: XCD = (b + 32*qt) % 8 = b % 8).
// LDS: 8 + 4 + 10 + 1 = 23 KB -> 4 blocks/CU fits easily.
__global__ __launch_bounds__(512, 8) void score_all(
    const float* __restrict__ ej, const float* __restrict__ ek2,
    const float* __restrict__ v, const float* __restrict__ keys,
    float* __restrict__ out_ctx, float* __restrict__ out_sc) {
    __shared__ float ejs[2][1024];       // 8 KB
    __shared__ float vs[1024];           // 4 KB
    __shared__ float red[8][64][5];      // 10 KB (stride 5 -> conflict-free)
    __shared__ float sc[2][128];         // 1 KB
    const float L2E = 1.4426950408889634f;
    int b = blockIdx.x, qt = blockIdx.y;
    int q0 = qt * 2;
    int tid = threadIdx.x;
    float vsum = v[1024];

    {   // stage ej (2 rows x 1024) + v (1024) into LDS, fully coalesced
        int j = tid >> 8, uu = (tid & 255) * 4;
        *(float4*)&ejs[j][uu] =
            *(const float4*)(ej + ((q0 + j) * 32 + b) * 1024 + uu);
        if (tid < 256) *(float4*)&vs[tid * 4] = *(const float4*)(v + tid * 4);
    }
    __syncthreads();

    int kp = tid & 63, uc = tid >> 6;
    const float* ekp = ek2 + (b * 1024 + uc * 128) * 128 + kp * 2;

    float a[2][2];
#pragma unroll
    for (int j = 0; j < 2; j++) { a[j][0] = 0.f; a[j][1] = 0.f; }

#pragma unroll 2
    for (int ui = 0; ui < 128; ui += 4) {
        float2 e0 = *(const float2*)(ekp);          // ek2[u]  [2k]
        float2 e1 = *(const float2*)(ekp + 128);    // ek2[u+1][2k]
        float2 e2 = *(const float2*)(ekp + 256);
        float2 e3 = *(const float2*)(ekp + 384);
        ekp += 512;
        float4 vv = *(const float4*)&vs[uc * 128 + ui];
#pragma unroll
        for (int j = 0; j < 2; j++) {
            float4 ee = *(const float4*)&ejs[j][uc * 128 + ui];
            float A1 = fmaf(ee.x, e0.x, 1.f);
            float B1 = fmaf(ee.y, e1.x, 1.f);
            a[j][0] = fmaf(fmaf(vv.x, B1, vv.y * A1),
                           __builtin_amdgcn_rcpf(A1 * B1), a[j][0]);
            float A2 = fmaf(ee.x, e0.y, 1.f);
            float B2 = fmaf(ee.y, e1.y, 1.f);
            a[j][1] = fmaf(fmaf(vv.x, B2, vv.y * A2),
                           __builtin_amdgcn_rcpf(A2 * B2), a[j][1]);
            float C1 = fmaf(ee.z, e2.x, 1.f);
            float D1 = fmaf(ee.w, e3.x, 1.f);
            a[j][0] = fmaf(fmaf(vv.z, D1, vv.w * C1),
                           __builtin_amdgcn_rcpf(C1 * D1), a[j][0]);
            float C2 = fmaf(ee.z, e2.y, 1.f);
            float D2 = fmaf(ee.w, e3.y, 1.f);
            a[j][1] = fmaf(fmaf(vv.z, D2, vv.w * C2),
                           __builtin_amdgcn_rcpf(C2 * D2), a[j][1]);
        }
    }

    // combine the 8 uc partials per (q, k) through LDS
#pragma unroll
    for (int j = 0; j < 2; j++) {
        red[uc][kp][j * 2 + 0] = a[j][0];
        red[uc][kp][j * 2 + 1] = a[j][1];
    }
    __syncthreads();
    if (tid < 256) {
        int j = tid >> 7, k = tid & 127;
        int kp2 = k >> 1, c = k & 1;
        float s = 0.f;
#pragma unroll
        for (int u = 0; u < 8; u++) s += red[u][kp2][j * 2 + c];
        sc[j][k] = vsum - 2.f * s;
    }
    __syncthreads();

    // softmax over k (128): waves 0..1 handle q-row j=w; lanes cover k, k+64
    int w = tid >> 6, lane = tid & 63;
    if (w < 2) {
        int j = w;
        float s1 = sc[j][lane], s2 = sc[j][lane + 64];
        float m = wave_max(fmaxf(s1, s2));
        float e1 = __builtin_amdgcn_exp2f((s1 - m) * L2E);
        float e2 = __builtin_amdgcn_exp2f((s2 - m) * L2E);
        float ssum = wave_sum(e1 + e2);
        float inv = __builtin_amdgcn_rcpf(ssum);
        float p1 = e1 * inv, p2 = e2 * inv;
        sc[j][lane] = p1; sc[j][lane + 64] = p2;
        float* o = out_sc + ((q0 + j) * 32 + b) * 128;
        o[lane] = p1; o[lane + 64] = p2;
    }
    __syncthreads();

    // context[j][n] = sum_k p[j][k] * keys[k][b][n]; thread owns 2 n, 2 rows
    {
        int n0 = tid * 2;
        const float* kbase = keys + b * 1024 + n0;
        float2 c0{0.f, 0.f}, c1{0.f, 0.f};
#pragma unroll 4
        for (int k = 0; k < 128; k++) {
            float2 kv = *(const float2*)(kbase + k * 32768);
            float s0 = sc[0][k], s1 = sc[1][k];
            c0.x = fmaf(s0, kv.x, c0.x); c0.y = fmaf(s0, kv.y, c0.y);
            c1.x = fmaf(s1, kv.x, c1.x); c1.y = fmaf(s1, kv.y, c1.y);
        }
        *(float2*)(out_ctx + ((q0 + 0) * 32 + b) * 1024 + n0) = c0;
        *(float2*)(out_ctx + ((q0 + 1) * 32 + b) * 1024 + n0) = c1;
    }
}

extern "C" void kernel_launch(void* const* d_in, const int* in_sizes, int n_in,
                              void* d_out, int out_size, void* d_ws, size_t ws_size,
                              hipStream_t stream) {
    const float* query = (const float*)d_in[0];
    const float* keys  = (const float*)d_in[1];
    const float* Wq    = (const float*)d_in[2];
    const float* Wk    = (const float*)d_in[3];
    const float* la    = (const float*)d_in[4];
    const float* ns    = (const float*)d_in[5];
    const float* bias  = (const float*)d_in[6];

    float* out_ctx = (float*)d_out;             // 64*32*1024
    float* out_sc  = (float*)d_out + 2097152;   // 64*32*128

    char* ws = (char*)d_ws;                     // ~38 MB used
    float* v   = (float*)(ws);                  // 1025 floats
    float* ej  = (float*)(ws + 8192);           // 8 MB  [2048 rows][1024 u]
    float* ek2 = (float*)(ws + 8192 + 8388608); // 16 MB [b][u][k]
    unsigned short* qb  = (unsigned short*)(ws + 8192 + 8388608 + 16777216);
    unsigned short* kb  = qb + 2097152;
    unsigned short* wqb = kb + 4194304;
    unsigned short* wkb = wqb + 1048576;

    convert_kernel<<<8193, 256, 0, stream>>>(query, keys, Wq, Wk, qb, kb, wqb, wkb,
                                             la, ns, v);
    proj_gemm<<<dim3(8, 96), 256, 0, stream>>>(qb, kb, wqb, wkb, bias, ej, ek2);
    score_all<<<dim3(32, 32), 512, 0, stream>>>(ej, ek2, v, keys, out_ctx, out_sc);
}

// Round 10
// 149.156 us; speedup vs baseline: 1.1236x; 1.1236x over previous
//
#include <hip/hip_runtime.h>
#include <stdint.h>

// Problem constants: t_q=64, t_k=128, b=32, n=1024
//   query (64,32,1024) f32 ; keys (128,32,1024) f32 ; Wq,Wk (1024,1024) f32
//   out0 = context (64,32,1024) f32 ; out1 = scores_softmax (64,32,128) f32
//
// Pipeline v11:
//  1) convert: f32->bf16 (q,k,Wq,Wk) + vnorm
//  2) proj_gemm (BK=128, 768 blocks; best measured config):
//       q-side ej = exp2((q*Wq^T + bias)*C2);
//       k-side ek2 = exp2((k*Wk^T)*C2) stored TRANSPOSED [b][u][k]
//  3) score_all v11: v3 merged structure (4 q / block, softmax + GEMV fused),
//     but thread owns a k-QUAD (4 k): ek2 loads are float4 (16 B) with fixed
//     512 B offsets -> half the load count, 2x cells per load vs v3.
//     Same per-cell math (pairing identity), zero cross-lane ops.

typedef __attribute__((ext_vector_type(8))) short bf16x8;
typedef __attribute__((ext_vector_type(4))) float f32x4;

#define C2_SCALE 2.8853900817779268f   // 2*log2(e)

__device__ __forceinline__ unsigned short f2bf(float x) {
    union { float f; uint32_t u; } v; v.f = x;
    uint32_t u = v.u;
    u += 0x7fffu + ((u >> 16) & 1u);   // round-to-nearest-even
    return (unsigned short)(u >> 16);
}

__device__ __forceinline__ float wave_sum(float x) {
#pragma unroll
    for (int off = 32; off; off >>= 1) x += __shfl_xor(x, off);
    return x;
}
__device__ __forceinline__ float wave_max(float x) {
#pragma unroll
    for (int off = 32; off; off >>= 1) x = fmaxf(x, __shfl_xor(x, off));
    return x;
}

// async 16B global -> LDS (wave-uniform base + lane*16 semantics)
__device__ __forceinline__ void gl2lds16(const void* g, void* l) {
    __builtin_amdgcn_global_load_lds(
        (const __attribute__((address_space(1))) void*)g,
        (__attribute__((address_space(3))) void*)l, 16, 0, 0);
}

// ------- f32 -> bf16 conversion of all 4 tensors + fused vnorm (blk 8192) ---
__global__ __launch_bounds__(256) void convert_kernel(
    const float* __restrict__ q, const float* __restrict__ k,
    const float* __restrict__ wq, const float* __restrict__ wk,
    unsigned short* __restrict__ qb, unsigned short* __restrict__ kb,
    unsigned short* __restrict__ wqb, unsigned short* __restrict__ wkb,
    const float* __restrict__ la, const float* __restrict__ ns,
    float* __restrict__ v) {
    __shared__ float red[4], red2[4];
    if (blockIdx.x == 8192) {
        // vnorm: v = la/||la|| * ns; v[1024] = sum(v)
        int tid = threadIdx.x, w = tid >> 6;
        float s = 0.f;
        for (int i = tid; i < 1024; i += 256) { float x = la[i]; s += x * x; }
        s = wave_sum(s);
        if ((tid & 63) == 0) red[w] = s;
        __syncthreads();
        float scale = rsqrtf(red[0] + red[1] + red[2] + red[3]) * ns[0];
        float vp = 0.f;
        for (int i = tid; i < 1024; i += 256) { float vv = la[i] * scale; v[i] = vv; vp += vv; }
        vp = wave_sum(vp);
        if ((tid & 63) == 0) red2[w] = vp;
        __syncthreads();
        if (tid == 0) v[1024] = red2[0] + red2[1] + red2[2] + red2[3];
        return;
    }
    int idx = blockIdx.x * 256 + threadIdx.x;   // float4 index; 2097152 total
    int e = idx * 4;
    const float* src; unsigned short* dst; int off;
    if (e < 2097152)      { src = q;  dst = qb;  off = e; }
    else if (e < 6291456) { src = k;  dst = kb;  off = e - 2097152; }
    else if (e < 7340032) { src = wq; dst = wqb; off = e - 6291456; }
    else                  { src = wk; dst = wkb; off = e - 7340032; }
    float4 xv = *(const float4*)(src + off);
    ushort4 o;
    o.x = f2bf(xv.x); o.y = f2bf(xv.y); o.z = f2bf(xv.z); o.w = f2bf(xv.w);
    *(ushort4*)(dst + off) = o;
}

// ---------------- combined projection GEMM (bf16 -> f32), BK=128 ------------
// Row-group swizzle: XCD = linear_id % 8 = blockIdx.x (since 8 | 8*y).
//   rowt = blockIdx.x * 12 + (blockIdx.y >> 3)   (0..95)
//   col0 = (blockIdx.y & 7) * 128
// rowt 0..31  -> q-part: rows (q*32+b) consecutive, arow = rowt*64
//                epilogue: ej[row][col] = exp2((acc + bias[col])*C2)
// rowt 32..95 -> k-part: t = rowt-32: b0 = t&31, k0 = (t>>5)*64
//                row set = {(k0+s)*32 + b0 : s = 0..63}  (fixed b!)
//                epilogue: LDS transpose -> ek2[(b0*1024+u)*128 + k]
// 64-row x 128-col tile, BK=128: 8 K-iters x (12 gl2lds + 32 MFMA).
// LDS 16+32 KB; epilogue 33 KB aliases. Grid (8, 96) = 768 blocks (3/CU).
// XOR swizzle: LDS[row][c] = global[row][c ^ (row&15)], c = 8-elem chunk 0..15
__global__ __launch_bounds__(256) void proj_gemm(
    const unsigned short* __restrict__ qb, const unsigned short* __restrict__ kb,
    const unsigned short* __restrict__ wqb, const unsigned short* __restrict__ wkb,
    const float* __restrict__ bias,
    float* __restrict__ ej, float* __restrict__ ek2) {
    __shared__ __align__(16) unsigned char smem[49152];
    unsigned short* As = (unsigned short*)smem;             // 16 KB [64][128]
    unsigned short* Bs = (unsigned short*)(smem + 16384);   // 32 KB [128][128]
    float* ep = (float*)smem;                               // 33 KB, k-epilogue only

    int col0 = (blockIdx.y & 7) * 128;
    int rowt = blockIdx.x * 12 + (blockIdx.y >> 3);   // 0..95
    int tid = threadIdx.x;
    int w = tid >> 6, lane = tid & 63;
    int wm = w >> 1, wn = w & 1;          // 2x2 waves
    int ml = lane & 15, quad = lane >> 4;

    bool is_k = rowt >= 32;
    const unsigned short* A; const unsigned short* Bm;
    int base, rstride, arow = 0, b0 = 0, k0g = 0;
    if (!is_k) {
        A = qb; Bm = wqb; arow = rowt * 64;
        base = arow * 1024; rstride = 1024;
    } else {
        int t = rowt - 32;
        b0 = t & 31; k0g = (t >> 5) * 64;
        A = kb; Bm = wkb;
        base = (k0g * 32 + b0) * 1024; rstride = 32 * 1024;
    }

    // staging: 16 lanes/row (256B = BK), 16 rows per gl2lds call
    int srow = tid >> 4;                       // 0..15
    int kxor = (tid & 15) ^ srow;              // row&15 == srow for all calls
    const unsigned short* ga = A + base + srow * rstride + kxor * 8;
    const unsigned short* gb = Bm + (col0 + srow) * 1024 + kxor * 8;
    unsigned short* la = &As[tid * 8];
    unsigned short* lb = &Bs[tid * 8];

    f32x4 acc[2][4];
#pragma unroll
    for (int i = 0; i < 2; i++)
#pragma unroll
        for (int j = 0; j < 4; j++) acc[i][j] = (f32x4)(0.f);

    for (int kk0 = 0; kk0 < 1024; kk0 += 128) {
        __syncthreads();
#pragma unroll
        for (int t = 0; t < 4; t++)
            gl2lds16(ga + t * 16 * rstride + kk0, la + t * 2048);
#pragma unroll
        for (int t = 0; t < 8; t++)
            gl2lds16(gb + t * 16 * 1024 + kk0, lb + t * 2048);
        __syncthreads();
#pragma unroll
        for (int ks = 0; ks < 4; ks++) {
            int kcol = ((ks * 4 + quad) ^ ml) * 8;
            bf16x8 a[2], b[4];
#pragma unroll
            for (int i = 0; i < 2; i++)
                a[i] = *(const bf16x8*)&As[(wm * 32 + i * 16 + ml) * 128 + kcol];
#pragma unroll
            for (int j = 0; j < 4; j++)
                b[j] = *(const bf16x8*)&Bs[(wn * 64 + j * 16 + ml) * 128 + kcol];
#pragma unroll
            for (int i = 0; i < 2; i++)
#pragma unroll
                for (int j = 0; j < 4; j++)
                    acc[i][j] = __builtin_amdgcn_mfma_f32_16x16x32_bf16(a[i], b[j], acc[i][j], 0, 0, 0);
        }
    }

    // C/D layout: col = lane&15, row = quad*4 + reg
    if (!is_k) {
        // q-part: ej = exp2((acc + bias)*C2), straight row-major store
#pragma unroll
        for (int i = 0; i < 2; i++)
#pragma unroll
            for (int j = 0; j < 4; j++) {
                int colg = col0 + wn * 64 + j * 16 + ml;
                float bj = bias[colg];
#pragma unroll
                for (int r = 0; r < 4; r++) {
                    int row = arow + wm * 32 + i * 16 + quad * 4 + r;
                    ej[row * 1024 + colg] =
                        __builtin_amdgcn_exp2f((acc[i][j][r] + bj) * C2_SCALE);
                }
            }
    } else {
        // k-part: exp2, restage through LDS, store transposed (k innermost)
        __syncthreads();   // all waves done reading As/Bs before ep overwrite
#pragma unroll
        for (int i = 0; i < 2; i++)
#pragma unroll
            for (int j = 0; j < 4; j++) {
                int col = wn * 64 + j * 16 + ml;
#pragma unroll
                for (int r = 0; r < 4; r++) {
                    int krel = wm * 32 + i * 16 + quad * 4 + r;
                    ep[krel * 129 + col] =
                        __builtin_amdgcn_exp2f(acc[i][j][r] * C2_SCALE);
                }
            }
        __syncthreads();
        int ur = tid >> 4;            // 0..15
        int kq = (tid & 15) * 4;      // k quad base 0..60
#pragma unroll
        for (int it = 0; it < 8; it++) {
            int u = it * 16 + ur;     // 0..127
            float4 o;
            o.x = ep[(kq + 0) * 129 + u];
            o.y = ep[(kq + 1) * 129 + u];
            o.z = ep[(kq + 2) * 129 + u];
            o.w = ep[(kq + 3) * 129 + u];
            *(float4*)(ek2 + (b0 * 1024 + col0 + u) * 128 + k0g + kq) = o;
        }
    }
}

// ---------------- merged score + softmax + context, k-quad loads ------------
// Grid (32 b, 16 qt) = 512 blocks, 512 thr -> 2 blocks/CU (LDS 54 KB).
// Phase 1: thread (kq = tid&31 k-QUAD, uc = tid>>5 owning 64 u). Per 4-u
//   step: 4 float4 ek2 loads (16 B, fixed 512 B offsets -> offset-immediate
//   addressing) cover 4u x 4k; with 4 q-rows = 64 cells per 4 loads (2x v3).
//   ej[4][1024] + v[1024] broadcast from LDS (<=2 addrs/wave = free).
//   Pairing identity: v0/(1+A)+v1/(1+B) = (v0*B1+v1*A1)*rcp(A1*B1).
// Phase 2: red2[16][4][128] contiguous (b128 writes / stride-1 reads,
//   conflict-free) -> sc = vsum - 2*s; softmax once; out_sc.
// Phase 3: context GEMV (2 n x 4 q per thread; keys slab L2-resident,
//   XCD = b%8).
__global__ __launch_bounds__(512, 4) void score_all(
    const float* __restrict__ ej, const float* __restrict__ ek2,
    const float* __restrict__ v, const float* __restrict__ keys,
    float* __restrict__ out_ctx, float* __restrict__ out_sc) {
    __shared__ float ejs[4][1024];       // 16 KB
    __shared__ float vs[1024];           // 4 KB
    __shared__ float red2[16][4][128];   // 32 KB
    __shared__ float sc[4][128];         // 2 KB
    const float L2E = 1.4426950408889634f;
    int b = blockIdx.x, qt = blockIdx.y;
    int q0 = qt * 4;
    int tid = threadIdx.x;
    float vsum = v[1024];

    {   // stage ej (4 rows x 1024) + v (1024) into LDS, fully coalesced
        int j = tid >> 7, uu = (tid & 127) * 8;
        const float* src = ej + ((q0 + j) * 32 + b) * 1024 + uu;
        *(float4*)&ejs[j][uu] = *(const float4*)(src);
        *(float4*)&ejs[j][uu + 4] = *(const float4*)(src + 4);
        if (tid < 256) *(float4*)&vs[tid * 4] = *(const float4*)(v + tid * 4);
    }
    __syncthreads();

    int kq = tid & 31, uc = tid >> 5;    // k-quad 0..31, u-chunk 0..15 (64 u)
    const float* ekp = ek2 + (b * 1024 + uc * 64) * 128 + kq * 4;

    float a[4][4];
#pragma unroll
    for (int j = 0; j < 4; j++)
#pragma unroll
        for (int c = 0; c < 4; c++) a[j][c] = 0.f;

#pragma unroll 2
    for (int st = 0; st < 16; st++) {        // 4 u per step
        f32x4 e0 = *(const f32x4*)(ekp);         // ek2[u  ][4k]
        f32x4 e1 = *(const f32x4*)(ekp + 128);   // ek2[u+1][4k]
        f32x4 e2 = *(const f32x4*)(ekp + 256);   // ek2[u+2][4k]
        f32x4 e3 = *(const f32x4*)(ekp + 384);   // ek2[u+3][4k]
        ekp += 512;
        int ua = uc * 64 + st * 4;
        float4 vv = *(const float4*)&vs[ua];
#pragma unroll
        for (int j = 0; j < 4; j++) {
            float4 ee = *(const float4*)&ejs[j][ua];
#pragma unroll
            for (int c = 0; c < 4; c++) {
                float A1 = fmaf(ee.x, e0[c], 1.f);
                float B1 = fmaf(ee.y, e1[c], 1.f);
                a[j][c] = fmaf(fmaf(vv.x, B1, vv.y * A1),
                               __builtin_amdgcn_rcpf(A1 * B1), a[j][c]);
                float C1 = fmaf(ee.z, e2[c], 1.f);
                float D1 = fmaf(ee.w, e3[c], 1.f);
                a[j][c] = fmaf(fmaf(vv.z, D1, vv.w * C1),
                               __builtin_amdgcn_rcpf(C1 * D1), a[j][c]);
            }
        }
    }

    // combine the 16 uc partials per (q, k): contiguous b128 writes
#pragma unroll
    for (int j = 0; j < 4; j++) {
        f32x4 t = {a[j][0], a[j][1], a[j][2], a[j][3]};
        *(f32x4*)&red2[uc][j][kq * 4] = t;
    }
    __syncthreads();
    {
        int j = tid >> 7, k = tid & 127;
        float s = 0.f;
#pragma unroll
        for (int u = 0; u < 16; u++) s += red2[u][j][k];
        sc[j][k] = vsum - 2.f * s;
    }
    __syncthreads();

    // softmax over k (128): waves 0..3 handle q-row j=w; lanes cover k, k+64
    int w = tid >> 6, lane = tid & 63;
    if (w < 4) {
        int j = w;
        float s1 = sc[j][lane], s2 = sc[j][lane + 64];
        float m = wave_max(fmaxf(s1, s2));
        float e1 = __builtin_amdgcn_exp2f((s1 - m) * L2E);
        float e2 = __builtin_amdgcn_exp2f((s2 - m) * L2E);
        float ssum = wave_sum(e1 + e2);
        float inv = __builtin_amdgcn_rcpf(ssum);
        float p1 = e1 * inv, p2 = e2 * inv;
        sc[j][lane] = p1; sc[j][lane + 64] = p2;
        float* o = out_sc + ((q0 + j) * 32 + b) * 128;
        o[lane] = p1; o[lane + 64] = p2;
    }
    __syncthreads();

    // context[j][n] = sum_k p[j][k] * keys[k][b][n]; thread owns 2 n, 4 rows
    {
        int n0 = tid * 2;
        const float* kbase = keys + b * 1024 + n0;
        float2 c0{0.f, 0.f}, c1{0.f, 0.f}, c2{0.f, 0.f}, c3{0.f, 0.f};
#pragma unroll 2
        for (int k = 0; k < 128; k++) {
            float2 kv = *(const float2*)(kbase + k * 32768);
            float s0 = sc[0][k], s1 = sc[1][k], s2 = sc[2][k], s3 = sc[3][k];
            c0.x = fmaf(s0, kv.x, c0.x); c0.y = fmaf(s0, kv.y, c0.y);
            c1.x = fmaf(s1, kv.x, c1.x); c1.y = fmaf(s1, kv.y, c1.y);
            c2.x = fmaf(s2, kv.x, c2.x); c2.y = fmaf(s2, kv.y, c2.y);
            c3.x = fmaf(s3, kv.x, c3.x); c3.y = fmaf(s3, kv.y, c3.y);
        }
        *(float2*)(out_ctx + ((q0 + 0) * 32 + b) * 1024 + n0) = c0;
        *(float2*)(out_ctx + ((q0 + 1) * 32 + b) * 1024 + n0) = c1;
        *(float2*)(out_ctx + ((q0 + 2) * 32 + b) * 1024 + n0) = c2;
        *(float2*)(out_ctx + ((q0 + 3) * 32 + b) * 1024 + n0) = c3;
    }
}

extern "C" void kernel_launch(void* const* d_in, const int* in_sizes, int n_in,
                              void* d_out, int out_size, void* d_ws, size_t ws_size,
                              hipStream_t stream) {
    const float* query = (const float*)d_in[0];
    const float* keys  = (const float*)d_in[1];
    const float* Wq    = (const float*)d_in[2];
    const float* Wk    = (const float*)d_in[3];
    const float* la    = (const float*)d_in[4];
    const float* ns    = (const float*)d_in[5];
    const float* bias  = (const float*)d_in[6];

    float* out_ctx = (float*)d_out;             // 64*32*1024
    float* out_sc  = (float*)d_out + 2097152;   // 64*32*128

    char* ws = (char*)d_ws;                     // ~38 MB used
    float* v   = (float*)(ws);                  // 1025 floats
    float* ej  = (float*)(ws + 8192);           // 8 MB  [2048 rows][1024 u]
    float* ek2 = (float*)(ws + 8192 + 8388608); // 16 MB [b][u][k]
    unsigned short* qb  = (unsigned short*)(ws + 8192 + 8388608 + 16777216);
    unsigned short* kb  = qb + 2097152;
    unsigned short* wqb = kb + 4194304;
    unsigned short* wkb = wqb + 1048576;

    convert_kernel<<<8193, 256, 0, stream>>>(query, keys, Wq, Wk, qb, kb, wqb, wkb,
                                             la, ns, v);
    proj_gemm<<<dim3(8, 96), 256, 0, stream>>>(qb, kb, wqb, wkb, bias, ej, ek2);
    score_all<<<dim3(32, 16), 512, 0, stream>>>(ej, ek2, v, keys, out_ctx, out_sc);
}